// Round 1
// baseline (3545.542 us; speedup 1.0000x reference)
//
#include <hip/hip_runtime.h>
#include <math.h>

#define NN 100000
#define EE 1600000
#define CC 128
#define FPD 512
#define GG 1024
#define LLAYERS 3

// ---------------- CSR build ----------------

__global__ __launch_bounds__(256) void count_kernel(const int* __restrict__ row,
                                                    int* __restrict__ deg, int e) {
  int i = blockIdx.x * 256 + threadIdx.x;
  if (i < e) atomicAdd(&deg[row[i]], 1);
}

__global__ __launch_bounds__(256) void scan_kernel(const int* __restrict__ deg,
                                                   int* __restrict__ rowptr,
                                                   int* __restrict__ cursor, int n) {
  __shared__ int wsum[4];
  __shared__ int runsh;
  int t = threadIdx.x;
  int lane = t & 63, wid = t >> 6;
  if (t == 0) runsh = 0;
  __syncthreads();
  for (int base = 0; base < n; base += 1024) {
    int idx = base + t * 4;
    int d0 = (idx + 0 < n) ? deg[idx + 0] : 0;
    int d1 = (idx + 1 < n) ? deg[idx + 1] : 0;
    int d2 = (idx + 2 < n) ? deg[idx + 2] : 0;
    int d3 = (idx + 3 < n) ? deg[idx + 3] : 0;
    int s = d0 + d1 + d2 + d3;
    int inc = s;
#pragma unroll
    for (int off = 1; off < 64; off <<= 1) {
      int o = __shfl_up(inc, off, 64);
      if (lane >= off) inc += o;
    }
    if (lane == 63) wsum[wid] = inc;
    __syncthreads();
    int woff = 0;
    for (int w = 0; w < wid; w++) woff += wsum[w];
    int total = wsum[0] + wsum[1] + wsum[2] + wsum[3];
    int run0 = runsh;
    int p = run0 + woff + (inc - s);
    if (idx + 0 < n) { rowptr[idx + 0] = p; cursor[idx + 0] = p; } p += d0;
    if (idx + 1 < n) { rowptr[idx + 1] = p; cursor[idx + 1] = p; } p += d1;
    if (idx + 2 < n) { rowptr[idx + 2] = p; cursor[idx + 2] = p; } p += d2;
    if (idx + 3 < n) { rowptr[idx + 3] = p; cursor[idx + 3] = p; }
    __syncthreads();
    if (t == 0) runsh = run0 + total;
    __syncthreads();
  }
  if (t == 0) rowptr[n] = runsh;
}

__global__ __launch_bounds__(256) void fill_kernel(const int* __restrict__ row,
                                                   const int* __restrict__ col,
                                                   int* __restrict__ cursor,
                                                   int* __restrict__ colidx, int e) {
  int i = blockIdx.x * 256 + threadIdx.x;
  if (i < e) {
    int r = row[i];
    int pos = atomicAdd(&cursor[r], 1);
    colidx[pos] = col[i];
  }
}

// ---------------- per-layer kernels ----------------

// u = x @ Ws^T, v = x @ Wn^T   (biases added later in neigh_tanh)
// block: 256 threads, 32 nodes; thread tile: 2 mats x 4 nodes x 4 contiguous cols
__global__ __launch_bounds__(256) void gemm2_kernel(const float* __restrict__ x,
                                                    const float* __restrict__ Wsl,
                                                    const float* __restrict__ Wnl,
                                                    float* __restrict__ u,
                                                    float* __restrict__ v) {
  __shared__ float xs[32 * 132];  // 32 rows, stride 132 floats (pad 4)
  int t = threadIdx.x;
  long long nb = (long long)blockIdx.x * 32;
  const float4* xg = (const float4*)(x + nb * CC);
#pragma unroll
  for (int i = 0; i < 4; i++) {
    int idx = t + i * 256;          // 0..1023 float4s, 32 per row
    int n = idx >> 5, k4 = idx & 31;
    ((float4*)(xs + n * 132))[k4] = xg[idx];
  }
  __syncthreads();
  int cg = t & 31;   // cols cg*4..cg*4+3 (per matrix)
  int ng = t >> 5;   // nodes ng*4..ng*4+3
  int c0 = cg * 4;
  float acc[2][4][4];  // [mat][node][col]
#pragma unroll
  for (int m = 0; m < 2; m++)
#pragma unroll
    for (int j = 0; j < 4; j++)
#pragma unroll
      for (int i = 0; i < 4; i++) acc[m][j][i] = 0.f;
  const float4* Ws4 = (const float4*)(Wsl + c0 * CC);
  const float4* Wn4 = (const float4*)(Wnl + c0 * CC);
#pragma unroll 4
  for (int kc = 0; kc < 32; kc++) {
    float4 w[2][4], xr[4];
#pragma unroll
    for (int i = 0; i < 4; i++) {
      w[0][i] = Ws4[i * 32 + kc];
      w[1][i] = Wn4[i * 32 + kc];
    }
#pragma unroll
    for (int j = 0; j < 4; j++) xr[j] = ((const float4*)(xs + (ng * 4 + j) * 132))[kc];
#pragma unroll
    for (int m = 0; m < 2; m++)
#pragma unroll
      for (int j = 0; j < 4; j++)
#pragma unroll
        for (int i = 0; i < 4; i++) {
          acc[m][j][i] = fmaf(w[m][i].x, xr[j].x, acc[m][j][i]);
          acc[m][j][i] = fmaf(w[m][i].y, xr[j].y, acc[m][j][i]);
          acc[m][j][i] = fmaf(w[m][i].z, xr[j].z, acc[m][j][i]);
          acc[m][j][i] = fmaf(w[m][i].w, xr[j].w, acc[m][j][i]);
        }
  }
#pragma unroll
  for (int j = 0; j < 4; j++) {
    long long n = nb + ng * 4 + j;
    float4 us = make_float4(acc[0][j][0], acc[0][j][1], acc[0][j][2], acc[0][j][3]);
    float4 vs = make_float4(acc[1][j][0], acc[1][j][1], acc[1][j][2], acc[1][j][3]);
    ((float4*)(u + n * CC))[cg] = us;
    ((float4*)(v + n * CC))[cg] = vs;
  }
}

// x_out[n] = tanh(u[n] + bias + sum_{e in row n} v[colidx[e]])
// block: 256 threads = 2 nodes x 128 channels
__global__ __launch_bounds__(256) void neigh_tanh_kernel(const float* __restrict__ u,
                                                         const float* __restrict__ v,
                                                         const int* __restrict__ rowptr,
                                                         const int* __restrict__ colidx,
                                                         const float* __restrict__ bsl,
                                                         const float* __restrict__ bnl,
                                                         float* __restrict__ xout) {
  int t = threadIdx.x;
  long long n = (long long)blockIdx.x * 2 + (t >> 7);
  int c = t & 127;
  float s = u[n * CC + c] + bsl[c] + bnl[c];
  int e0 = rowptr[n], e1 = rowptr[n + 1];
  for (int e = e0; e < e1; e++) {
    int col = colidx[e];
    s += v[(long long)col * CC + c];
  }
  xout[n * CC + c] = tanhf(s);
}

// logits = x @ Wfp^T ; softmax over 512; fingerprint[batch[n]] += probs
// block: 256 threads, 16 nodes; thread tile: 8 nodes x 4 contiguous fp-cols
__global__ __launch_bounds__(256) void fp_kernel(const float* __restrict__ x,
                                                 const float* __restrict__ Wfpl,
                                                 const int* __restrict__ batch,
                                                 float* __restrict__ out) {
  __shared__ float xs[16 * 132];
  __shared__ float lt[16 * 516];  // 16 nodes x 512 logits, stride 516
  __shared__ int gsh[16];
  int t = threadIdx.x;
  long long nb = (long long)blockIdx.x * 16;
  const float4* xg = (const float4*)(x + nb * CC);
#pragma unroll
  for (int i = 0; i < 2; i++) {
    int idx = t + i * 256;  // 0..511 float4s
    int n = idx >> 5, k4 = idx & 31;
    ((float4*)(xs + n * 132))[k4] = xg[idx];
  }
  if (t < 16) gsh[t] = batch[nb + t];
  __syncthreads();

  int fg = t & 127;  // fp cols fg*4..fg*4+3
  int ng = t >> 7;   // nodes ng*8..ng*8+7
  int f0 = fg * 4;
  float acc[8][4];
#pragma unroll
  for (int j = 0; j < 8; j++)
#pragma unroll
    for (int i = 0; i < 4; i++) acc[j][i] = 0.f;
  const float4* W4 = (const float4*)(Wfpl + (long long)f0 * CC);
#pragma unroll 2
  for (int kc = 0; kc < 32; kc++) {
    float4 w[4], xr[8];
#pragma unroll
    for (int i = 0; i < 4; i++) w[i] = W4[i * 32 + kc];
#pragma unroll
    for (int j = 0; j < 8; j++) xr[j] = ((const float4*)(xs + (ng * 8 + j) * 132))[kc];
#pragma unroll
    for (int j = 0; j < 8; j++)
#pragma unroll
      for (int i = 0; i < 4; i++) {
        acc[j][i] = fmaf(w[i].x, xr[j].x, acc[j][i]);
        acc[j][i] = fmaf(w[i].y, xr[j].y, acc[j][i]);
        acc[j][i] = fmaf(w[i].z, xr[j].z, acc[j][i]);
        acc[j][i] = fmaf(w[i].w, xr[j].w, acc[j][i]);
      }
  }
#pragma unroll
  for (int j = 0; j < 8; j++) {
    int n = ng * 8 + j;
    *(float4*)(lt + n * 516 + f0) = make_float4(acc[j][0], acc[j][1], acc[j][2], acc[j][3]);
  }
  __syncthreads();

  // softmax: one node per wave per pass, conflict-free 64-lane rows
  int lane = t & 63, wid = t >> 6;
#pragma unroll
  for (int pass = 0; pass < 4; pass++) {
    int n = pass * 4 + wid;
    float* rowp = lt + n * 516;
    float vr[8];
    float mx = -3.4e38f;
#pragma unroll
    for (int j = 0; j < 8; j++) {
      vr[j] = rowp[lane + j * 64];
      mx = fmaxf(mx, vr[j]);
    }
#pragma unroll
    for (int off = 32; off >= 1; off >>= 1) mx = fmaxf(mx, __shfl_xor(mx, off, 64));
    float sum = 0.f;
#pragma unroll
    for (int j = 0; j < 8; j++) {
      vr[j] = expf(vr[j] - mx);
      sum += vr[j];
    }
#pragma unroll
    for (int off = 32; off >= 1; off >>= 1) sum += __shfl_xor(sum, off, 64);
    float inv = 1.0f / sum;
#pragma unroll
    for (int j = 0; j < 8; j++) rowp[lane + j * 64] = vr[j] * inv;
  }
  __syncthreads();

  // segment-sum into fingerprint: batch is sorted, run-length accumulate
#pragma unroll
  for (int half = 0; half < 2; half++) {
    int f = t + half * 256;
    float a = 0.f;
    int gprev = gsh[0];
#pragma unroll
    for (int i = 0; i < 16; i++) {
      int g = gsh[i];  // uniform across threads -> no divergence
      if (g != gprev) {
        atomicAdd(&out[(long long)gprev * FPD + f], a);
        a = 0.f;
        gprev = g;
      }
      a += lt[i * 516 + f];
    }
    atomicAdd(&out[(long long)gprev * FPD + f], a);
  }
}

// ---------------- launch ----------------

extern "C" void kernel_launch(void* const* d_in, const int* in_sizes, int n_in,
                              void* d_out, int out_size, void* d_ws, size_t ws_size,
                              hipStream_t stream) {
  (void)in_sizes; (void)n_in; (void)ws_size;
  const float* x   = (const float*)d_in[0];
  const float* Ws  = (const float*)d_in[1];
  const float* bs  = (const float*)d_in[2];
  const float* Wn  = (const float*)d_in[3];
  const float* bn  = (const float*)d_in[4];
  const float* Wfp = (const float*)d_in[5];
  const int*   ei  = (const int*)d_in[6];
  const int*   bat = (const int*)d_in[7];
  float* out = (float*)d_out;

  // workspace layout
  float* P0 = (float*)d_ws;
  float* P1 = P0 + (size_t)NN * CC;
  float* P2 = P1 + (size_t)NN * CC;
  int* deg    = (int*)(P2 + (size_t)NN * CC);
  int* rowptr = deg + NN;
  int* cursor = rowptr + (NN + 1);
  int* colidx = cursor + NN;

  hipMemsetAsync(d_out, 0, (size_t)out_size * sizeof(float), stream);
  hipMemsetAsync(deg, 0, (size_t)NN * sizeof(int), stream);

  const int* erow = ei;
  const int* ecol = ei + EE;
  count_kernel<<<(EE + 255) / 256, 256, 0, stream>>>(erow, deg, EE);
  scan_kernel<<<1, 256, 0, stream>>>(deg, rowptr, cursor, NN);
  fill_kernel<<<(EE + 255) / 256, 256, 0, stream>>>(erow, ecol, cursor, colidx, EE);

  const float* xin = x;
  for (int l = 0; l < LLAYERS; l++) {
    float *U, *V, *XO;
    if (l == 0)      { U = P0; V = P1; XO = P2; }
    else if (l == 1) { U = P0; V = P1; XO = P0; }  // XO alias U is safe (per-element read-then-write)
    else             { U = P1; V = P2; XO = P1; }
    gemm2_kernel<<<NN / 32, 256, 0, stream>>>(xin, Ws + (size_t)l * CC * CC,
                                              Wn + (size_t)l * CC * CC, U, V);
    neigh_tanh_kernel<<<NN / 2, 256, 0, stream>>>(U, V, rowptr, colidx,
                                                  bs + (size_t)l * CC, bn + (size_t)l * CC, XO);
    fp_kernel<<<NN / 16, 256, 0, stream>>>(XO, Wfp + (size_t)l * FPD * CC, bat, out);
    xin = XO;
  }
}

// Round 2
// 3397.923 us; speedup vs baseline: 1.0434x; 1.0434x over previous
//
#include <hip/hip_runtime.h>
#include <math.h>

#define NN 100000
#define EE 1600000
#define CC 128
#define FPD 512
#define GG 1024
#define LLAYERS 3

// ---------------- CSR build ----------------

__global__ __launch_bounds__(256) void count_kernel(const int* __restrict__ row,
                                                    int* __restrict__ deg, int e) {
  int i = blockIdx.x * 256 + threadIdx.x;
  if (i < e) atomicAdd(&deg[row[i]], 1);
}

__global__ __launch_bounds__(256) void scan_kernel(const int* __restrict__ deg,
                                                   int* __restrict__ rowptr,
                                                   int* __restrict__ cursor, int n) {
  __shared__ int wsum[4];
  __shared__ int runsh;
  int t = threadIdx.x;
  int lane = t & 63, wid = t >> 6;
  if (t == 0) runsh = 0;
  __syncthreads();
  for (int base = 0; base < n; base += 1024) {
    int idx = base + t * 4;
    int d0 = (idx + 0 < n) ? deg[idx + 0] : 0;
    int d1 = (idx + 1 < n) ? deg[idx + 1] : 0;
    int d2 = (idx + 2 < n) ? deg[idx + 2] : 0;
    int d3 = (idx + 3 < n) ? deg[idx + 3] : 0;
    int s = d0 + d1 + d2 + d3;
    int inc = s;
#pragma unroll
    for (int off = 1; off < 64; off <<= 1) {
      int o = __shfl_up(inc, off, 64);
      if (lane >= off) inc += o;
    }
    if (lane == 63) wsum[wid] = inc;
    __syncthreads();
    int woff = 0;
    for (int w = 0; w < wid; w++) woff += wsum[w];
    int total = wsum[0] + wsum[1] + wsum[2] + wsum[3];
    int run0 = runsh;
    int p = run0 + woff + (inc - s);
    if (idx + 0 < n) { rowptr[idx + 0] = p; cursor[idx + 0] = p; } p += d0;
    if (idx + 1 < n) { rowptr[idx + 1] = p; cursor[idx + 1] = p; } p += d1;
    if (idx + 2 < n) { rowptr[idx + 2] = p; cursor[idx + 2] = p; } p += d2;
    if (idx + 3 < n) { rowptr[idx + 3] = p; cursor[idx + 3] = p; }
    __syncthreads();
    if (t == 0) runsh = run0 + total;
    __syncthreads();
  }
  if (t == 0) rowptr[n] = runsh;
}

__global__ __launch_bounds__(256) void fill_kernel(const int* __restrict__ row,
                                                   const int* __restrict__ col,
                                                   int* __restrict__ cursor,
                                                   int* __restrict__ colidx, int e) {
  int i = blockIdx.x * 256 + threadIdx.x;
  if (i < e) {
    int r = row[i];
    int pos = atomicAdd(&cursor[r], 1);
    colidx[pos] = col[i];
  }
}

// ---------------- per-layer kernels ----------------

// Ax[n] = sum_{e in row n} x[colidx[e]]   (gather-first; matches reference order)
// block: 256 threads = 8 nodes x 32 float4-lanes
__global__ __launch_bounds__(256) void gather_kernel(const float* __restrict__ x,
                                                     const int* __restrict__ rowptr,
                                                     const int* __restrict__ colidx,
                                                     float* __restrict__ ax) {
  int t = threadIdx.x;
  long long n = (long long)blockIdx.x * 8 + (t >> 5);
  int q = t & 31;
  int e0 = rowptr[n], e1 = rowptr[n + 1];
  float4 s0 = make_float4(0.f, 0.f, 0.f, 0.f);
  float4 s1 = make_float4(0.f, 0.f, 0.f, 0.f);
  int e = e0;
  for (; e + 4 <= e1; e += 4) {
    int c0 = colidx[e], c1 = colidx[e + 1], c2 = colidx[e + 2], c3 = colidx[e + 3];
    float4 v0 = ((const float4*)(x + (long long)c0 * CC))[q];
    float4 v1 = ((const float4*)(x + (long long)c1 * CC))[q];
    float4 v2 = ((const float4*)(x + (long long)c2 * CC))[q];
    float4 v3 = ((const float4*)(x + (long long)c3 * CC))[q];
    s0.x += v0.x; s0.y += v0.y; s0.z += v0.z; s0.w += v0.w;
    s1.x += v1.x; s1.y += v1.y; s1.z += v1.z; s1.w += v1.w;
    s0.x += v2.x; s0.y += v2.y; s0.z += v2.z; s0.w += v2.w;
    s1.x += v3.x; s1.y += v3.y; s1.z += v3.z; s1.w += v3.w;
  }
  for (; e < e1; e++) {
    int c0 = colidx[e];
    float4 v0 = ((const float4*)(x + (long long)c0 * CC))[q];
    s0.x += v0.x; s0.y += v0.y; s0.z += v0.z; s0.w += v0.w;
  }
  float4 s = make_float4(s0.x + s1.x, s0.y + s1.y, s0.z + s1.z, s0.w + s1.w);
  ((float4*)(ax + n * CC))[q] = s;
}

// xout = tanh(x @ Ws^T + Ax @ Wn^T + bs + bn)   (fused K=256 GEMM + epilogue)
// block: 256 threads, 32 nodes; thread tile: 4 nodes x 4 contiguous cols
__global__ __launch_bounds__(256, 4) void gemm_tanh_kernel(const float* __restrict__ x,
                                                           const float* __restrict__ ax,
                                                           const float* __restrict__ Wsl,
                                                           const float* __restrict__ Wnl,
                                                           const float* __restrict__ bsl,
                                                           const float* __restrict__ bnl,
                                                           float* __restrict__ xout) {
  __shared__ float xs[32 * 132];
  __shared__ float as_[32 * 132];
  int t = threadIdx.x;
  long long nb = (long long)blockIdx.x * 32;
  const float4* xg = (const float4*)(x + nb * CC);
  const float4* ag = (const float4*)(ax + nb * CC);
#pragma unroll
  for (int i = 0; i < 4; i++) {
    int idx = t + i * 256;          // 0..1023 float4s, 32 per row
    int n = idx >> 5, k4 = idx & 31;
    ((float4*)(xs + n * 132))[k4] = xg[idx];
    ((float4*)(as_ + n * 132))[k4] = ag[idx];
  }
  __syncthreads();
  int cg = t & 31;   // out cols cg*4..cg*4+3
  int ng = t >> 5;   // nodes ng*4..ng*4+3
  int c0 = cg * 4;
  float acc[4][4];
#pragma unroll
  for (int j = 0; j < 4; j++)
#pragma unroll
    for (int i = 0; i < 4; i++) acc[j][i] = 0.f;
  const float4* Ws4 = (const float4*)(Wsl + c0 * CC);
  const float4* Wn4 = (const float4*)(Wnl + c0 * CC);
#pragma unroll 4
  for (int kc = 0; kc < 32; kc++) {
    float4 w[4], xr[4];
#pragma unroll
    for (int i = 0; i < 4; i++) w[i] = Ws4[i * 32 + kc];
#pragma unroll
    for (int j = 0; j < 4; j++) xr[j] = ((const float4*)(xs + (ng * 4 + j) * 132))[kc];
#pragma unroll
    for (int j = 0; j < 4; j++)
#pragma unroll
      for (int i = 0; i < 4; i++) {
        acc[j][i] = fmaf(w[i].x, xr[j].x, acc[j][i]);
        acc[j][i] = fmaf(w[i].y, xr[j].y, acc[j][i]);
        acc[j][i] = fmaf(w[i].z, xr[j].z, acc[j][i]);
        acc[j][i] = fmaf(w[i].w, xr[j].w, acc[j][i]);
      }
  }
#pragma unroll 4
  for (int kc = 0; kc < 32; kc++) {
    float4 w[4], xr[4];
#pragma unroll
    for (int i = 0; i < 4; i++) w[i] = Wn4[i * 32 + kc];
#pragma unroll
    for (int j = 0; j < 4; j++) xr[j] = ((const float4*)(as_ + (ng * 4 + j) * 132))[kc];
#pragma unroll
    for (int j = 0; j < 4; j++)
#pragma unroll
      for (int i = 0; i < 4; i++) {
        acc[j][i] = fmaf(w[i].x, xr[j].x, acc[j][i]);
        acc[j][i] = fmaf(w[i].y, xr[j].y, acc[j][i]);
        acc[j][i] = fmaf(w[i].z, xr[j].z, acc[j][i]);
        acc[j][i] = fmaf(w[i].w, xr[j].w, acc[j][i]);
      }
  }
  float b0 = bsl[c0 + 0] + bnl[c0 + 0];
  float b1 = bsl[c0 + 1] + bnl[c0 + 1];
  float b2 = bsl[c0 + 2] + bnl[c0 + 2];
  float b3 = bsl[c0 + 3] + bnl[c0 + 3];
#pragma unroll
  for (int j = 0; j < 4; j++) {
    long long n = nb + ng * 4 + j;
    float4 o = make_float4(tanhf(acc[j][0] + b0), tanhf(acc[j][1] + b1),
                           tanhf(acc[j][2] + b2), tanhf(acc[j][3] + b3));
    ((float4*)(xout + n * CC))[cg] = o;
  }
}

// logits = x @ Wfp^T ; softmax over 512 (register-resident); fingerprint[batch[n]] += probs
// block: 256 threads, 16 nodes; thread tile: 8 nodes x 4 contiguous fp-cols
// softmax reduction: 64-lane shuffle + 2-wave LDS exchange (waves 2g,2g+1 share node group g)
__global__ __launch_bounds__(256, 4) void fp_kernel(const float* __restrict__ x,
                                                    const float* __restrict__ Wfpl,
                                                    const int* __restrict__ batch,
                                                    float* __restrict__ out) {
  __shared__ float xs[16 * 132];
  __shared__ float redm[32];  // [wave(4)][node(8)]
  __shared__ float reds[32];
  __shared__ int gsh[16];
  int t = threadIdx.x;
  long long nb = (long long)blockIdx.x * 16;
  const float4* xg = (const float4*)(x + nb * CC);
#pragma unroll
  for (int i = 0; i < 2; i++) {
    int idx = t + i * 256;  // 0..511 float4s
    int n = idx >> 5, k4 = idx & 31;
    ((float4*)(xs + n * 132))[k4] = xg[idx];
  }
  if (t < 16) gsh[t] = batch[nb + t];
  __syncthreads();

  int fg = t & 127;  // fp cols fg*4..fg*4+3
  int ng = t >> 7;   // nodes ng*8..ng*8+7
  int f0 = fg * 4;
  float acc[8][4];
#pragma unroll
  for (int j = 0; j < 8; j++)
#pragma unroll
    for (int i = 0; i < 4; i++) acc[j][i] = 0.f;
  const float4* W4 = (const float4*)(Wfpl + (long long)f0 * CC);
#pragma unroll 2
  for (int kc = 0; kc < 32; kc++) {
    float4 w[4], xr[8];
#pragma unroll
    for (int i = 0; i < 4; i++) w[i] = W4[i * 32 + kc];
#pragma unroll
    for (int j = 0; j < 8; j++) xr[j] = ((const float4*)(xs + (ng * 8 + j) * 132))[kc];
#pragma unroll
    for (int j = 0; j < 8; j++)
#pragma unroll
      for (int i = 0; i < 4; i++) {
        acc[j][i] = fmaf(w[i].x, xr[j].x, acc[j][i]);
        acc[j][i] = fmaf(w[i].y, xr[j].y, acc[j][i]);
        acc[j][i] = fmaf(w[i].z, xr[j].z, acc[j][i]);
        acc[j][i] = fmaf(w[i].w, xr[j].w, acc[j][i]);
      }
  }

  int lane = t & 63, wv = t >> 6;
  // --- max over 512 cols per node ---
  float mx[8];
#pragma unroll
  for (int j = 0; j < 8; j++) {
    float m = fmaxf(fmaxf(acc[j][0], acc[j][1]), fmaxf(acc[j][2], acc[j][3]));
#pragma unroll
    for (int off = 32; off >= 1; off >>= 1) m = fmaxf(m, __shfl_xor(m, off, 64));
    mx[j] = m;
  }
  if (lane == 0) {
#pragma unroll
    for (int j = 0; j < 8; j++) redm[wv * 8 + j] = mx[j];
  }
  __syncthreads();
#pragma unroll
  for (int j = 0; j < 8; j++)
    mx[j] = fmaxf(redm[(2 * ng) * 8 + j], redm[(2 * ng + 1) * 8 + j]);

  // --- exp + sum ---
  float sm[8];
#pragma unroll
  for (int j = 0; j < 8; j++) {
#pragma unroll
    for (int i = 0; i < 4; i++) acc[j][i] = __expf(acc[j][i] - mx[j]);
    float s = (acc[j][0] + acc[j][1]) + (acc[j][2] + acc[j][3]);
#pragma unroll
    for (int off = 32; off >= 1; off >>= 1) s += __shfl_xor(s, off, 64);
    sm[j] = s;
  }
  if (lane == 0) {
#pragma unroll
    for (int j = 0; j < 8; j++) reds[wv * 8 + j] = sm[j];
  }
  __syncthreads();
  float inv[8];
#pragma unroll
  for (int j = 0; j < 8; j++)
    inv[j] = 1.0f / (reds[(2 * ng) * 8 + j] + reds[(2 * ng + 1) * 8 + j]);

  // --- segment-sum into fingerprint (batch sorted -> run-length in registers) ---
  float a0 = 0.f, a1 = 0.f, a2 = 0.f, a3 = 0.f;
  int gprev = gsh[ng * 8];
#pragma unroll
  for (int j = 0; j < 8; j++) {
    int g = gsh[ng * 8 + j];  // uniform across the 128 threads of this ng
    if (g != gprev) {
      float* base = &out[(long long)gprev * FPD + f0];
      atomicAdd(base + 0, a0); atomicAdd(base + 1, a1);
      atomicAdd(base + 2, a2); atomicAdd(base + 3, a3);
      a0 = a1 = a2 = a3 = 0.f;
      gprev = g;
    }
    a0 += acc[j][0] * inv[j];
    a1 += acc[j][1] * inv[j];
    a2 += acc[j][2] * inv[j];
    a3 += acc[j][3] * inv[j];
  }
  float* base = &out[(long long)gprev * FPD + f0];
  atomicAdd(base + 0, a0); atomicAdd(base + 1, a1);
  atomicAdd(base + 2, a2); atomicAdd(base + 3, a3);
}

// ---------------- launch ----------------

extern "C" void kernel_launch(void* const* d_in, const int* in_sizes, int n_in,
                              void* d_out, int out_size, void* d_ws, size_t ws_size,
                              hipStream_t stream) {
  (void)in_sizes; (void)n_in; (void)ws_size;
  const float* x   = (const float*)d_in[0];
  const float* Ws  = (const float*)d_in[1];
  const float* bs  = (const float*)d_in[2];
  const float* Wn  = (const float*)d_in[3];
  const float* bn  = (const float*)d_in[4];
  const float* Wfp = (const float*)d_in[5];
  const int*   ei  = (const int*)d_in[6];
  const int*   bat = (const int*)d_in[7];
  float* out = (float*)d_out;

  // workspace layout
  float* P0 = (float*)d_ws;
  float* P1 = P0 + (size_t)NN * CC;
  float* P2 = P1 + (size_t)NN * CC;
  int* deg    = (int*)(P2 + (size_t)NN * CC);
  int* rowptr = deg + NN;
  int* cursor = rowptr + (NN + 1);
  int* colidx = cursor + NN;

  hipMemsetAsync(d_out, 0, (size_t)out_size * sizeof(float), stream);
  hipMemsetAsync(deg, 0, (size_t)NN * sizeof(int), stream);

  const int* erow = ei;
  const int* ecol = ei + EE;
  count_kernel<<<(EE + 255) / 256, 256, 0, stream>>>(erow, deg, EE);
  scan_kernel<<<1, 256, 0, stream>>>(deg, rowptr, cursor, NN);
  fill_kernel<<<(EE + 255) / 256, 256, 0, stream>>>(erow, ecol, cursor, colidx, EE);

  // buffer rotation: layer l reads xin, writes Ax into A, xout into XO
  const float* xin = x;
  float* bufA[3]  = {P0, P0, P0};
  float* bufXO[3] = {P1, P2, P1};
  for (int l = 0; l < LLAYERS; l++) {
    float* A  = bufA[l];
    float* XO = bufXO[l];
    gather_kernel<<<NN / 8, 256, 0, stream>>>(xin, rowptr, colidx, A);
    gemm_tanh_kernel<<<NN / 32, 256, 0, stream>>>(xin, A,
        Ws + (size_t)l * CC * CC, Wn + (size_t)l * CC * CC,
        bs + (size_t)l * CC, bn + (size_t)l * CC, XO);
    fp_kernel<<<NN / 16, 256, 0, stream>>>(XO, Wfp + (size_t)l * FPD * CC, bat, out);
    xin = XO;
  }
}